// Round 9
// baseline (99.682 us; speedup 1.0000x reference)
//
#include <hip/hip_runtime.h>

// Acrobot GN step, fused bf16-MFMA. rows = 2*B, 32 rows per 2-wave WG tile.
//   G1: e1  = relu(A1 @ in32)            A1=[We1[10:17];be1]^T, K=32; B built in regs
//   G2: e2  = relu(A2 @ e1 + be2)        A2=We2^T, K=128; be2 via MFMA C-init
//   G3: hdd = relu(A3 @ [e2[row^1]; sender,1]) K=160; bn1 folded in A3ext col2
//   G4: delta = A4 @ hdd + bn2           A4=Wn2^T pad [16][128]; bn2 via C-init; direct store
//
// R8 post-mortem: 2-barrier cross-tile pipeline regressed (44.5 vs 40.4) — limiter is
// TLP (2 waves/SIMD from 128 AGPR weight residency) vs ~3k-cycle per-tile dep path,
// not barrier count. R9: revert to R7 3-barrier loop; stream ALL weight fragments from
// global (L2-resident 72KB, LICM defeated via opaque "+s" asm) -> no resident weights;
// LDS 24KB; waves_per_eu(3,3) -> 170-reg budget -> 3 waves/SIMD, 6 WGs/CU, grid 2048.

typedef __attribute__((ext_vector_type(8))) short bf16x8;
typedef __attribute__((ext_vector_type(4))) float f32x4;

union U4B { uint4 u; bf16x8 b; };

__device__ __forceinline__ unsigned short f2bf(float f) {
  union { float f; unsigned u; } v; v.f = f;
  return (unsigned short)((v.u + 0x7FFFu + ((v.u >> 16) & 1u)) >> 16);  // RNE
}

__device__ __forceinline__ unsigned cvtpk(float lo, float hi) {
  unsigned r;
  asm("v_cvt_pk_bf16_f32 %0, %1, %2" : "=v"(r) : "v"(lo), "v"(hi));
  return r;
}

// ---------------- weight prep: bf16 A-operand images in ws ----------------
// shorts: A1c [128j][8k] @0 ; A3e [128j][8k] @1024 ; A4c [2jp][128k] @2048 (2304 total);
//         A2 [128j][128k] @4096 ; A3 main [128j][128k] @20480. 36864 shorts = 73728 B.
__global__ void gn_prep(const float* __restrict__ We1, const float* __restrict__ be1,
                        const float* __restrict__ We2, const float* __restrict__ Wn1,
                        const float* __restrict__ bn1, const float* __restrict__ Wn2,
                        unsigned short* __restrict__ wsA) {
  int t = blockIdx.x * 256 + threadIdx.x;
  if (t < 1024) {                       // A1 compact: k<7 -> We1 rows 10..16 ; k==7 -> be1
    int j = t >> 3, k = t & 7;
    wsA[t] = f2bf((k < 7) ? We1[(10 + k) * 128 + j] : be1[j]);
  } else if (t < 2048) {                // A3ext compact: c0=Wn1r10, c1=Wn1r11, c2=bn1
    int t2 = t - 1024; int j = t2 >> 3, c = t2 & 7;
    float v = (c == 0) ? Wn1[10 * 128 + j] : (c == 1) ? Wn1[11 * 128 + j]
            : (c == 2) ? bn1[j] : 0.0f;
    wsA[t] = f2bf(v);
  } else if (t < 2304) {                // A4 compact: 2 rows of Wn2^T
    int t2 = t - 2048; int jp = t2 >> 7, k = t2 & 127;
    wsA[t] = f2bf(Wn2[k * 2 + jp]);
  } else if (t >= 4096 && t < 20480) {  // A2 = We2^T
    int t2 = t - 4096; int j = t2 >> 7, k = t2 & 127;
    wsA[t] = f2bf(We2[k * 128 + j]);
  } else if (t >= 20480 && t < 36864) { // A3 main = Wn1[12:140]^T
    int t2 = t - 20480; int j = t2 >> 7, k = t2 & 127;
    wsA[t] = f2bf(Wn1[(12 + k) * 128 + j]);
  }
}

// ---------------- main fused kernel ----------------
#define NTILES 8192   // 262144 rows / 32 rows per tile
#define GRID   2048   // 4 tiles per WG

__global__ __launch_bounds__(128) __attribute__((amdgpu_waves_per_eu(3, 3)))
void gn_main(
    const float* __restrict__ x, const float* __restrict__ u,
    const float* __restrict__ nmean, const float* __restrict__ nstd,
    const float* __restrict__ emean, const float* __restrict__ estd,
    const float* __restrict__ be2, const float* __restrict__ bn2,
    const unsigned short* __restrict__ wsA,
    float* __restrict__ out)
{
  __shared__ __align__(16) unsigned short bufE1[32 * 128];  // 8KB
  __shared__ __align__(16) unsigned short bufE2[32 * 128];  // 8KB
  __shared__ __align__(16) unsigned short bufHD[32 * 128];  // 8KB  -> 24KB total

  const int tid  = threadIdx.x;
  const int lane = tid & 63;
  const int Mg   = tid >> 6;     // wave = feature half 0/1
  const int c15  = lane & 15;
  const int g    = lane >> 4;    // 0..3

  const int jbw = Mg * 64;

  const float nm0 = nmean[0], nm1 = nmean[1];
  const float is0 = 1.0f / nstd[0], is1 = 1.0f / nstd[1];
  const float em0 = emean[0], ie0 = 1.0f / estd[0];
  const float cea1 = (0.0f - emean[1]) / estd[1];
  const float cea2 = (0.0f - emean[2]) / estd[2];
  const float bn20 = bn2[0], bn21 = bn2[1];
  const unsigned cpkw = cvtpk(cea2, 1.0f);   // B dword3: [cea2, 1.0]

  // ---- prefetch first tile's x/u ----
  float4 xv[2]; float uv[2];
  if (g == 0) {
    #pragma unroll
    for (int n = 0; n < 2; ++n) {
      int b = blockIdx.x * 16 + n * 8 + (c15 >> 1);
      xv[n] = *(const float4*)(x + b * 4);
      uv[n] = u[b];
    }
  }

  for (int tile = blockIdx.x; tile < NTILES; tile += GRID) {
    const int rowbase = tile * 32;

    // Opaque copy of the weight base pointer: prevents LICM/CSE from hoisting the
    // per-tile fragment loads into loop-carried registers (which would spill).
    const unsigned short* wsT = wsA;
    asm volatile("" : "+s"(wsT));

    // ---------- A1 transient fragments (global, L2-hot) ----------
    bf16x8 A1t[4];
    #pragma unroll
    for (int m = 0; m < 4; ++m) {
      uint4 av = (uint4){0u, 0u, 0u, 0u};
      if (g == 0) av = *(const uint4*)(wsT + (jbw + m * 16 + c15) * 8);
      U4B ta; ta.u = av; A1t[m] = ta.b;
    }

    // ---------- build G1 B-operands in registers ----------
    unsigned pks[2];
    bf16x8 Bv[2];
    #pragma unroll
    for (int n = 0; n < 2; ++n) {
      uint4 bu = (uint4){0u, 0u, 0u, 0u};
      if (g == 0) {                     // only k=0..7 nonzero; g==0 lanes hold them
        float a0 = (xv[n].x - nm0) * is0;   // node0 theta
        float a1 = (xv[n].z - nm1) * is1;   // node0 v
        float b0 = (xv[n].y - nm0) * is0;   // node1 theta
        float b1 = (xv[n].w - nm1) * is1;   // node1 v
        bool  e  = (c15 & 1);               // row parity = edge index
        float s0 = e ? b0 : a0, s1 = e ? b1 : a1;   // sender  feats
        float r0 = e ? a0 : b0, r1 = e ? a1 : b1;   // receiver feats
        float ea0 = (uv[n] - em0) * ie0;
        bu.x = cvtpk(s0, s1);
        bu.y = cvtpk(r0, r1);
        bu.z = cvtpk(ea0, cea1);
        bu.w = cpkw;
      }
      pks[n] = bu.x;                    // sender feats, reused as G3 node feats
      U4B t; t.u = bu; Bv[n] = t.b;
    }

    // ---------- prefetch next tile's x/u ----------
    {
      int nt = tile + GRID;
      if (nt < NTILES && g == 0) {
        #pragma unroll
        for (int n = 0; n < 2; ++n) {
          int b = nt * 16 + n * 8 + (c15 >> 1);
          xv[n] = *(const float4*)(x + b * 4);
          uv[n] = u[b];
        }
      }
    }

    f32x4 acc[4][2];

    // ---------- G1: e1 = relu(A1 @ in32) -> bufE1 ----------
    #pragma unroll
    for (int m = 0; m < 4; ++m)
      #pragma unroll
      for (int n = 0; n < 2; ++n) acc[m][n] = (f32x4){0.f, 0.f, 0.f, 0.f};
    #pragma unroll
    for (int n = 0; n < 2; ++n)
      #pragma unroll
      for (int m = 0; m < 4; ++m)
        acc[m][n] = __builtin_amdgcn_mfma_f32_16x16x32_bf16(A1t[m], Bv[n], acc[m][n], 0, 0, 0);
    #pragma unroll
    for (int m = 0; m < 4; ++m) {
      int jb2 = (jbw + m * 16 + g * 4) * 2;
      #pragma unroll
      for (int n = 0; n < 2; ++n) {
        int row = n * 16 + c15;
        f32x4 v = acc[m][n];
        uint2 pk;
        pk.x = cvtpk(fmaxf(v[0], 0.f), fmaxf(v[1], 0.f));
        pk.y = cvtpk(fmaxf(v[2], 0.f), fmaxf(v[3], 0.f));
        *(uint2*)((char*)bufE1 + row * 256 + (jb2 ^ ((row & 7) << 4))) = pk;
      }
    }
    __syncthreads();

    // ---------- G2: e2 = relu(A2 @ e1 + be2) -> bufE2 (be2 as C-init) ----------
    #pragma unroll
    for (int m = 0; m < 4; ++m) {
      f32x4 bz = *(const f32x4*)(be2 + jbw + m * 16 + g * 4);
      acc[m][0] = bz; acc[m][1] = bz;
    }
    #pragma unroll
    for (int kk = 0; kk < 4; ++kk) {
      bf16x8 F[4];                      // transient A2 fragments (global, L2-hot)
      #pragma unroll
      for (int m = 0; m < 4; ++m)
        F[m] = *(const bf16x8*)(wsT + 4096 + (jbw + m * 16 + c15) * 128 + kk * 32 + g * 8);
      #pragma unroll
      for (int n = 0; n < 2; ++n) {
        int row = n * 16 + c15;
        bf16x8 B = *(const bf16x8*)((const char*)bufE1 + row * 256 + ((kk * 64 + g * 16) ^ ((row & 7) << 4)));
        #pragma unroll
        for (int m = 0; m < 4; ++m)
          acc[m][n] = __builtin_amdgcn_mfma_f32_16x16x32_bf16(F[m], B, acc[m][n], 0, 0, 0);
      }
    }
    #pragma unroll
    for (int m = 0; m < 4; ++m) {
      int jb2 = (jbw + m * 16 + g * 4) * 2;
      #pragma unroll
      for (int n = 0; n < 2; ++n) {
        int row = n * 16 + c15;
        f32x4 v = acc[m][n];
        uint2 pk;
        pk.x = cvtpk(fmaxf(v[0], 0.f), fmaxf(v[1], 0.f));
        pk.y = cvtpk(fmaxf(v[2], 0.f), fmaxf(v[3], 0.f));
        *(uint2*)((char*)bufE2 + row * 256 + (jb2 ^ ((row & 7) << 4))) = pk;
      }
    }
    __syncthreads();

    // ---------- G3: hdd = relu(A3 @ [e2[row^1]; sender,1]) -> bufHD ----------
    #pragma unroll
    for (int m = 0; m < 4; ++m)
      #pragma unroll
      for (int n = 0; n < 2; ++n) acc[m][n] = (f32x4){0.f, 0.f, 0.f, 0.f};
    #pragma unroll
    for (int kk = 0; kk < 4; ++kk) {
      bf16x8 F[4];                      // transient A3 fragments
      #pragma unroll
      for (int m = 0; m < 4; ++m)
        F[m] = *(const bf16x8*)(wsT + 20480 + (jbw + m * 16 + c15) * 128 + kk * 32 + g * 8);
      #pragma unroll
      for (int n = 0; n < 2; ++n) {
        int rsw = (n * 16 + c15) ^ 1;   // aggregation = paired-row swap
        bf16x8 B = *(const bf16x8*)((const char*)bufE2 + rsw * 256 + ((kk * 64 + g * 16) ^ ((rsw & 7) << 4)));
        #pragma unroll
        for (int m = 0; m < 4; ++m)
          acc[m][n] = __builtin_amdgcn_mfma_f32_16x16x32_bf16(F[m], B, acc[m][n], 0, 0, 0);
      }
    }
    {
      bf16x8 Fe[4];                     // transient A3ext fragments
      #pragma unroll
      for (int m = 0; m < 4; ++m) {
        uint4 av = (uint4){0u, 0u, 0u, 0u};
        if (g == 0) av = *(const uint4*)(wsT + 1024 + (jbw + m * 16 + c15) * 8);
        U4B ta; ta.u = av; Fe[m] = ta.b;
      }
      #pragma unroll
      for (int n = 0; n < 2; ++n) {
        // K-chunk 4: node feats (= sender feats saved from B-build) + const-1 (bn1 col)
        uint4 b4u = (uint4){0u, 0u, 0u, 0u};
        if (g == 0) { b4u.x = pks[n]; b4u.y = 0x00003F80u; }
        U4B t4; t4.u = b4u;
        #pragma unroll
        for (int m = 0; m < 4; ++m)
          acc[m][n] = __builtin_amdgcn_mfma_f32_16x16x32_bf16(Fe[m], t4.b, acc[m][n], 0, 0, 0);
      }
    }
    #pragma unroll
    for (int m = 0; m < 4; ++m) {
      int jb2 = (jbw + m * 16 + g * 4) * 2;
      #pragma unroll
      for (int n = 0; n < 2; ++n) {
        int row = n * 16 + c15;
        f32x4 v = acc[m][n];
        uint2 pk;
        pk.x = cvtpk(fmaxf(v[0], 0.f), fmaxf(v[1], 0.f));
        pk.y = cvtpk(fmaxf(v[2], 0.f), fmaxf(v[3], 0.f));
        *(uint2*)((char*)bufHD + row * 256 + (jb2 ^ ((row & 7) << 4))) = pk;
      }
    }
    __syncthreads();

    // ---------- G4: delta = A4 @ hdd + bn2 (C-init), store direct ----------
    {
      int rr = Mg * 16 + c15;
      int rb = rr * 256, sw = (rr & 7) << 4;
      f32x4 a4 = (f32x4){bn20, bn21, 0.f, 0.f};
      #pragma unroll
      for (int kk = 0; kk < 4; ++kk) {
        uint4 av = (uint4){0u, 0u, 0u, 0u};   // transient A4 fragment
        if (c15 < 2) av = *(const uint4*)(wsT + 2048 + c15 * 128 + kk * 32 + g * 8);
        U4B ta; ta.u = av;
        bf16x8 B = *(const bf16x8*)((const char*)bufHD + rb + ((kk * 64 + g * 16) ^ sw));
        a4 = __builtin_amdgcn_mfma_f32_16x16x32_bf16(ta.b, B, a4, 0, 0, 0);
      }
      if (g == 0) {                // lane holds delta c0,c1 for row rr
        int gr = rowbase + rr;
        int bidx = gr >> 1, k = gr & 1;
        out[bidx * 4 + k]     = x[bidx * 4 + k]     + a4[0];
        out[bidx * 4 + k + 2] = x[bidx * 4 + k + 2] + a4[1];
      }
    }
    // no trailing barrier: next G1 writes bufE1, whose last reads (G2) are 2 barriers back.
  }
}

extern "C" void kernel_launch(void* const* d_in, const int* in_sizes, int n_in,
                              void* d_out, int out_size, void* d_ws, size_t ws_size,
                              hipStream_t stream) {
  const float* x   = (const float*)d_in[0];
  const float* u   = (const float*)d_in[1];
  const float* nm  = (const float*)d_in[2];
  const float* ns  = (const float*)d_in[3];
  const float* em  = (const float*)d_in[4];
  const float* es  = (const float*)d_in[5];
  const float* We1 = (const float*)d_in[6];
  const float* be1 = (const float*)d_in[7];
  const float* We2 = (const float*)d_in[8];
  const float* be2 = (const float*)d_in[9];
  const float* Wn1 = (const float*)d_in[10];
  const float* bn1 = (const float*)d_in[11];
  const float* Wn2 = (const float*)d_in[12];
  const float* bn2 = (const float*)d_in[13];
  unsigned short* wsA = (unsigned short*)d_ws;   // needs 73728 bytes
  float* out = (float*)d_out;

  gn_prep<<<144, 256, 0, stream>>>(We1, be1, We2, Wn1, bn1, Wn2, wsA);
  gn_main<<<GRID, 128, 0, stream>>>(x, u, nm, ns, em, es, be2, bn2, wsA, out);
}

// Round 10
// 43.299 us; speedup vs baseline: 2.3022x; 2.3022x over previous
//
#include <hip/hip_runtime.h>

// Acrobot GN step, fused bf16-MFMA. rows = 2*B, 32 rows per 2-wave WG tile.
//   G1: e1  = relu(A1 @ in32)            A1=[We1[10:17];be1]^T, K=32; B built in regs
//   G2: e2  = relu(A2 @ e1 + be2)        A2=We2^T, K=128; be2 via MFMA C-init
//   G3: hdd = relu(A3 @ [e2[row^1]; sender,1]) K=160; bn1 folded in A3ext col2
//   G4: delta = Wn2^T @ hdd + bn2        FUSED into G3: f32 VALU dot on the acc regs,
//        shfl_xor g-reduce, cross-wave combine via 512B pd buffer (bufHD deleted)
//
// R9 post-mortem: streaming weights from L2 = 2.5x regression (latency in critical path);
// R7 AGPR-resident structure restored (40.4us, spill-free). R10 on top of R7:
//   - G3+G4 fusion (no bufHD round-trip, no padded G4 MFMAs, shorter 3rd phase)
//   - exec-mask removal on A1/A3ext loads (B-side zeros make A-side garbage harmless)
//   - s_setprio(1) around G2/G3 MFMA clusters
//   - opaque aLDS offset to defeat LICM hoisting of loop-invariant LDS reads

typedef __attribute__((ext_vector_type(8))) short bf16x8;
typedef __attribute__((ext_vector_type(4))) float f32x4;

union U4B { uint4 u; bf16x8 b; };

__device__ __forceinline__ unsigned short f2bf(float f) {
  union { float f; unsigned u; } v; v.f = f;
  return (unsigned short)((v.u + 0x7FFFu + ((v.u >> 16) & 1u)) >> 16);  // RNE
}

__device__ __forceinline__ unsigned cvtpk(float lo, float hi) {
  unsigned r;
  asm("v_cvt_pk_bf16_f32 %0, %1, %2" : "=v"(r) : "v"(lo), "v"(hi));
  return r;
}

// ---------------- weight prep: bf16 A-operand images in ws ----------------
// shorts: A1c [128j][8k] @0 ; A3e [128j][8k] @1024 ; wn2 cols f32[2][128] @2048 (bytes 4096);
//         A2 [128j][128k] @4096 ; A3 main [128j][128k] @20480. 36864 shorts = 73728 B.
__global__ void gn_prep(const float* __restrict__ We1, const float* __restrict__ be1,
                        const float* __restrict__ We2, const float* __restrict__ Wn1,
                        const float* __restrict__ bn1, const float* __restrict__ Wn2,
                        unsigned short* __restrict__ wsA) {
  int t = blockIdx.x * 256 + threadIdx.x;
  if (t < 1024) {                       // A1 compact: k<7 -> We1 rows 10..16 ; k==7 -> be1
    int j = t >> 3, k = t & 7;
    wsA[t] = f2bf((k < 7) ? We1[(10 + k) * 128 + j] : be1[j]);
  } else if (t < 2048) {                // A3ext compact: c0=Wn1r10, c1=Wn1r11, c2=bn1
    int t2 = t - 1024; int j = t2 >> 3, c = t2 & 7;
    float v = (c == 0) ? Wn1[10 * 128 + j] : (c == 1) ? Wn1[11 * 128 + j]
            : (c == 2) ? bn1[j] : 0.0f;
    wsA[t] = f2bf(v);
  } else if (t < 2304) {                // Wn2 columns, f32: [c][j]
    int f = t - 2048; int c = f >> 7, j = f & 127;
    ((float*)(wsA + 2048))[f] = Wn2[j * 2 + c];
  } else if (t >= 4096 && t < 20480) {  // A2 = We2^T
    int t2 = t - 4096; int j = t2 >> 7, k = t2 & 127;
    wsA[t] = f2bf(We2[k * 128 + j]);
  } else if (t >= 20480 && t < 36864) { // A3 main = Wn1[12:140]^T
    int t2 = t - 20480; int j = t2 >> 7, k = t2 & 127;
    wsA[t] = f2bf(Wn1[(12 + k) * 128 + j]);
  }
}

// ---------------- main fused kernel ----------------
#define NTILES 8192   // 262144 rows / 32 rows per tile
#define GRID   1024   // 8 tiles per WG; 4 WGs/CU resident

__global__ __launch_bounds__(128) __attribute__((amdgpu_waves_per_eu(2, 2)))
void gn_main(
    const float* __restrict__ x, const float* __restrict__ u,
    const float* __restrict__ nmean, const float* __restrict__ nstd,
    const float* __restrict__ emean, const float* __restrict__ estd,
    const float* __restrict__ be2, const float* __restrict__ bn2,
    const unsigned short* __restrict__ wsA,
    float* __restrict__ out)
{
  __shared__ __align__(16) unsigned short bufE1[32 * 128];  // 8KB
  __shared__ __align__(16) unsigned short bufE2[32 * 128];  // 8KB
  __shared__ __align__(16) unsigned short aLDS[2560];       // A1c|A3e|wn2cols, 5KB
  __shared__ __align__(16) float pd[128];                   // [Mg][row][c], 512B

  const int tid  = threadIdx.x;
  const int lane = tid & 63;
  const int Mg   = tid >> 6;     // wave = feature half 0/1
  const int c15  = lane & 15;
  const int g    = lane >> 4;    // 0..3

  const int jbw = Mg * 64;

  // ---- copy compact A-images + wn2 cols into LDS (one time) ----
  for (int t = tid; t < 1280; t += 128)
    ((unsigned*)aLDS)[t] = ((const unsigned*)wsA)[t];

  // ---- resident A-operand fragments: A2, A3-main (128 regs = AGPR capacity) ----
  bf16x8 A2f[4][4], A3f[4][4];
  #pragma unroll
  for (int m = 0; m < 4; ++m) {
    int j = jbw + m * 16 + c15;
    #pragma unroll
    for (int kk = 0; kk < 4; ++kk) {
      A2f[m][kk] = *(const bf16x8*)(wsA + 4096  + j * 128 + kk * 32 + g * 8);
      A3f[m][kk] = *(const bf16x8*)(wsA + 20480 + j * 128 + kk * 32 + g * 8);
    }
  }

  const float nm0 = nmean[0], nm1 = nmean[1];
  const float is0 = 1.0f / nstd[0], is1 = 1.0f / nstd[1];
  const float em0 = emean[0], ie0 = 1.0f / estd[0];
  const float cea1 = (0.0f - emean[1]) / estd[1];
  const float cea2 = (0.0f - emean[2]) / estd[2];
  const float bn20 = bn2[0], bn21 = bn2[1];
  const unsigned cpkw = cvtpk(cea2, 1.0f);   // B dword3: [cea2, 1.0]

  // ---- prefetch first tile's x/u ----
  float4 xv[2]; float uv[2];
  if (g == 0) {
    #pragma unroll
    for (int n = 0; n < 2; ++n) {
      int b = blockIdx.x * 16 + n * 8 + (c15 >> 1);
      xv[n] = *(const float4*)(x + b * 4);
      uv[n] = u[b];
    }
  }
  __syncthreads();   // aLDS ready

  for (int tile = blockIdx.x; tile < NTILES; tile += GRID) {
    const int rowbase = tile * 32;

    // opaque LDS offset: stop LICM from hoisting loop-invariant aLDS reads into regs
    unsigned aoff = 0;
    asm volatile("" : "+v"(aoff));
    const char* aB = (const char*)aLDS + aoff;

    // ---------- A1 transient fragments (LDS; garbage in g>0 lanes is harmless:
    //            the B operand is zero for k>=8) ----------
    bf16x8 A1t[4];
    #pragma unroll
    for (int m = 0; m < 4; ++m) {
      U4B ta; ta.u = *(const uint4*)(aB + (jbw + m * 16 + c15) * 16);
      A1t[m] = ta.b;
    }

    // ---------- build G1 B-operands in registers ----------
    unsigned pks[2];
    bf16x8 Bv[2];
    #pragma unroll
    for (int n = 0; n < 2; ++n) {
      uint4 bu = (uint4){0u, 0u, 0u, 0u};
      if (g == 0) {                     // only k=0..7 nonzero; g==0 lanes hold them
        float a0 = (xv[n].x - nm0) * is0;   // node0 theta
        float a1 = (xv[n].z - nm1) * is1;   // node0 v
        float b0 = (xv[n].y - nm0) * is0;   // node1 theta
        float b1 = (xv[n].w - nm1) * is1;   // node1 v
        bool  e  = (c15 & 1);               // row parity = edge index
        float s0 = e ? b0 : a0, s1 = e ? b1 : a1;   // sender  feats
        float r0 = e ? a0 : b0, r1 = e ? a1 : b1;   // receiver feats
        float ea0 = (uv[n] - em0) * ie0;
        bu.x = cvtpk(s0, s1);
        bu.y = cvtpk(r0, r1);
        bu.z = cvtpk(ea0, cea1);
        bu.w = cpkw;
      }
      pks[n] = bu.x;                    // sender feats, reused as G3 node feats
      U4B t; t.u = bu; Bv[n] = t.b;
    }

    // ---------- prefetch next tile's x/u ----------
    {
      int nt = tile + GRID;
      if (nt < NTILES && g == 0) {
        #pragma unroll
        for (int n = 0; n < 2; ++n) {
          int b = nt * 16 + n * 8 + (c15 >> 1);
          xv[n] = *(const float4*)(x + b * 4);
          uv[n] = u[b];
        }
      }
    }

    f32x4 acc[4][2];

    // ---------- G1: e1 = relu(A1 @ in32) -> bufE1 ----------
    #pragma unroll
    for (int m = 0; m < 4; ++m)
      #pragma unroll
      for (int n = 0; n < 2; ++n) acc[m][n] = (f32x4){0.f, 0.f, 0.f, 0.f};
    #pragma unroll
    for (int n = 0; n < 2; ++n)
      #pragma unroll
      for (int m = 0; m < 4; ++m)
        acc[m][n] = __builtin_amdgcn_mfma_f32_16x16x32_bf16(A1t[m], Bv[n], acc[m][n], 0, 0, 0);
    #pragma unroll
    for (int m = 0; m < 4; ++m) {
      int jb2 = (jbw + m * 16 + g * 4) * 2;
      #pragma unroll
      for (int n = 0; n < 2; ++n) {
        int row = n * 16 + c15;
        f32x4 v = acc[m][n];
        uint2 pk;
        pk.x = cvtpk(fmaxf(v[0], 0.f), fmaxf(v[1], 0.f));
        pk.y = cvtpk(fmaxf(v[2], 0.f), fmaxf(v[3], 0.f));
        *(uint2*)((char*)bufE1 + row * 256 + (jb2 ^ ((row & 7) << 4))) = pk;
      }
    }
    __syncthreads();                                   // bar1: e1 ready

    // ---------- G2: e2 = relu(A2 @ e1 + be2) -> bufE2 (be2 as C-init) ----------
    #pragma unroll
    for (int m = 0; m < 4; ++m) {
      f32x4 bz = *(const f32x4*)(be2 + jbw + m * 16 + g * 4);
      acc[m][0] = bz; acc[m][1] = bz;
    }
    __builtin_amdgcn_s_setprio(1);
    #pragma unroll
    for (int n = 0; n < 2; ++n) {
      int row = n * 16 + c15;
      int rb = row * 256, sw = (row & 7) << 4;
      #pragma unroll
      for (int kk = 0; kk < 4; ++kk) {
        bf16x8 B = *(const bf16x8*)((const char*)bufE1 + rb + ((kk * 64 + g * 16) ^ sw));
        #pragma unroll
        for (int m = 0; m < 4; ++m)
          acc[m][n] = __builtin_amdgcn_mfma_f32_16x16x32_bf16(A2f[m][kk], B, acc[m][n], 0, 0, 0);
      }
    }
    __builtin_amdgcn_s_setprio(0);
    #pragma unroll
    for (int m = 0; m < 4; ++m) {
      int jb2 = (jbw + m * 16 + g * 4) * 2;
      #pragma unroll
      for (int n = 0; n < 2; ++n) {
        int row = n * 16 + c15;
        f32x4 v = acc[m][n];
        uint2 pk;
        pk.x = cvtpk(fmaxf(v[0], 0.f), fmaxf(v[1], 0.f));
        pk.y = cvtpk(fmaxf(v[2], 0.f), fmaxf(v[3], 0.f));
        *(uint2*)((char*)bufE2 + row * 256 + (jb2 ^ ((row & 7) << 4))) = pk;
      }
    }
    __syncthreads();                                   // bar2: e2 ready

    // ---------- G3: hdd = relu(A3 @ [e2[row^1]; sender,1]) ; fused G4 dot ----------
    bf16x8 A3et[4];
    #pragma unroll
    for (int m = 0; m < 4; ++m) {       // transient ext fragments (no mask: B4 zero for g>0)
      U4B ta; ta.u = *(const uint4*)(aB + 2048 + (jbw + m * 16 + c15) * 16);
      A3et[m] = ta.b;
    }
    #pragma unroll
    for (int m = 0; m < 4; ++m)
      #pragma unroll
      for (int n = 0; n < 2; ++n) acc[m][n] = (f32x4){0.f, 0.f, 0.f, 0.f};
    __builtin_amdgcn_s_setprio(1);
    #pragma unroll
    for (int n = 0; n < 2; ++n) {
      int rsw = (n * 16 + c15) ^ 1;     // aggregation = paired-row swap
      int rb = rsw * 256, sw = (rsw & 7) << 4;
      #pragma unroll
      for (int kk = 0; kk < 4; ++kk) {
        bf16x8 B = *(const bf16x8*)((const char*)bufE2 + rb + ((kk * 64 + g * 16) ^ sw));
        #pragma unroll
        for (int m = 0; m < 4; ++m)
          acc[m][n] = __builtin_amdgcn_mfma_f32_16x16x32_bf16(A3f[m][kk], B, acc[m][n], 0, 0, 0);
      }
      // K-chunk 4: node feats (= sender feats saved from B-build) + const-1 (bn1 col)
      uint4 b4u = (uint4){0u, 0u, 0u, 0u};
      if (g == 0) { b4u.x = pks[n]; b4u.y = 0x00003F80u; }
      U4B t4; t4.u = b4u;
      #pragma unroll
      for (int m = 0; m < 4; ++m)
        acc[m][n] = __builtin_amdgcn_mfma_f32_16x16x32_bf16(A3et[m], t4.b, acc[m][n], 0, 0, 0);
    }
    __builtin_amdgcn_s_setprio(0);

    // fused G4: p[n][c] = sum_j relu(hdd[j]) * Wn2[j][c] over this wave's 16 j per lane
    {
      float p0[2] = {0.f, 0.f}, p1[2] = {0.f, 0.f};
      #pragma unroll
      for (int m = 0; m < 4; ++m) {
        int jo = (jbw + m * 16 + g * 4) * 4;           // byte offset into f32[128]
        f32x4 w0 = *(const f32x4*)(aB + 4096 + jo);    // Wn2 col0
        f32x4 w1 = *(const f32x4*)(aB + 4608 + jo);    // Wn2 col1
        #pragma unroll
        for (int n = 0; n < 2; ++n) {
          f32x4 v = acc[m][n];
          #pragma unroll
          for (int r = 0; r < 4; ++r) {
            float h = fmaxf(v[r], 0.f);
            p0[n] += h * w0[r];
            p1[n] += h * w1[r];
          }
        }
      }
      #pragma unroll
      for (int n = 0; n < 2; ++n) {                    // reduce over g (4 lane-groups)
        p0[n] += __shfl_xor(p0[n], 16, 64); p0[n] += __shfl_xor(p0[n], 32, 64);
        p1[n] += __shfl_xor(p1[n], 16, 64); p1[n] += __shfl_xor(p1[n], 32, 64);
      }
      if (g == 0) {
        #pragma unroll
        for (int n = 0; n < 2; ++n) {
          float2 w; w.x = p0[n]; w.y = p1[n];
          *(float2*)(pd + Mg * 64 + (n * 16 + c15) * 2) = w;
        }
      }
    }
    __syncthreads();                                   // bar3: pd ready

    // ---------- final: combine M-halves, add bn2 and x, store (wave 0) ----------
    if (tid < 64) {
      int row = tid >> 1, c = tid & 1;
      float d = pd[row * 2 + c] + pd[64 + row * 2 + c] + (c ? bn21 : bn20);
      int gr = rowbase + row;
      int bidx = gr >> 1, k = gr & 1;
      int gi = bidx * 4 + k + 2 * c;
      out[gi] = x[gi] + d;
    }
    // next G1 writes bufE1 (last read before bar2); pd rewritten only after next bar2. Safe.
  }
}

extern "C" void kernel_launch(void* const* d_in, const int* in_sizes, int n_in,
                              void* d_out, int out_size, void* d_ws, size_t ws_size,
                              hipStream_t stream) {
  const float* x   = (const float*)d_in[0];
  const float* u   = (const float*)d_in[1];
  const float* nm  = (const float*)d_in[2];
  const float* ns  = (const float*)d_in[3];
  const float* em  = (const float*)d_in[4];
  const float* es  = (const float*)d_in[5];
  const float* We1 = (const float*)d_in[6];
  const float* be1 = (const float*)d_in[7];
  const float* We2 = (const float*)d_in[8];
  const float* be2 = (const float*)d_in[9];
  const float* Wn1 = (const float*)d_in[10];
  const float* bn1 = (const float*)d_in[11];
  const float* Wn2 = (const float*)d_in[12];
  const float* bn2 = (const float*)d_in[13];
  unsigned short* wsA = (unsigned short*)d_ws;   // needs 73728 bytes
  float* out = (float*)d_out;

  gn_prep<<<144, 256, 0, stream>>>(We1, be1, We2, Wn1, bn1, Wn2, wsA);
  gn_main<<<GRID, 128, 0, stream>>>(x, u, nm, ns, em, es, be2, bn2, wsA, out);
}

// Round 11
// 41.112 us; speedup vs baseline: 2.4246x; 1.0532x over previous
//
#include <hip/hip_runtime.h>

// Acrobot GN step, fused bf16-MFMA. rows = 2*B, 32 rows per 4-wave WG tile.
//   G1: e1  = relu(A1 @ in32)            A1=[We1[10:17];be1]^T, K=32; B built in regs
//   G2: e2  = relu(A2 @ e1 + be2)        A2=We2^T, K=128; be2 via MFMA C-init
//   G3: hdd = relu(A3 @ [e2[row^1]; sender,1]) K=160; bn1 folded in A3ext col2
//   G4: delta = Wn2^T @ hdd + bn2        fused: f32 VALU dot + shfl g-reduce + pd buffer
//
// R10 post-mortem: fusion neutral (40.3us) -> loop is TLP-starved (2 waves/SIMD cover
// ~20% of the 12k-cyc tile-slot; R8/R9 showed rescheduling & de-residency both fail).
// R11: split features across 4 waves (Mq=32 feats each): resident AGPR 128->64,
// acc 32->16, total ~160 regs <= 170 = pool/3 -> waves_per_eu(3,3), 3 WGs/CU,
// 12 waves/CU (+50% TLP), 3 barrier domains. Grid 768 fully resident.

typedef __attribute__((ext_vector_type(8))) short bf16x8;
typedef __attribute__((ext_vector_type(4))) float f32x4;

union U4B { uint4 u; bf16x8 b; };

__device__ __forceinline__ unsigned short f2bf(float f) {
  union { float f; unsigned u; } v; v.f = f;
  return (unsigned short)((v.u + 0x7FFFu + ((v.u >> 16) & 1u)) >> 16);  // RNE
}

__device__ __forceinline__ unsigned cvtpk(float lo, float hi) {
  unsigned r;
  asm("v_cvt_pk_bf16_f32 %0, %1, %2" : "=v"(r) : "v"(lo), "v"(hi));
  return r;
}

// ---------------- weight prep: bf16 A-operand images in ws ----------------
// shorts: A1c [128j][8k] @0 ; A3e [128j][8k] @1024 ; wn2 cols f32[2][128] @2048 (bytes 4096);
//         A2 [128j][128k] @4096 ; A3 main [128j][128k] @20480. 36864 shorts = 73728 B.
__global__ void gn_prep(const float* __restrict__ We1, const float* __restrict__ be1,
                        const float* __restrict__ We2, const float* __restrict__ Wn1,
                        const float* __restrict__ bn1, const float* __restrict__ Wn2,
                        unsigned short* __restrict__ wsA) {
  int t = blockIdx.x * 256 + threadIdx.x;
  if (t < 1024) {                       // A1 compact: k<7 -> We1 rows 10..16 ; k==7 -> be1
    int j = t >> 3, k = t & 7;
    wsA[t] = f2bf((k < 7) ? We1[(10 + k) * 128 + j] : be1[j]);
  } else if (t < 2048) {                // A3ext compact: c0=Wn1r10, c1=Wn1r11, c2=bn1
    int t2 = t - 1024; int j = t2 >> 3, c = t2 & 7;
    float v = (c == 0) ? Wn1[10 * 128 + j] : (c == 1) ? Wn1[11 * 128 + j]
            : (c == 2) ? bn1[j] : 0.0f;
    wsA[t] = f2bf(v);
  } else if (t < 2304) {                // Wn2 columns, f32: [c][j]
    int f = t - 2048; int c = f >> 7, j = f & 127;
    ((float*)(wsA + 2048))[f] = Wn2[j * 2 + c];
  } else if (t >= 4096 && t < 20480) {  // A2 = We2^T
    int t2 = t - 4096; int j = t2 >> 7, k = t2 & 127;
    wsA[t] = f2bf(We2[k * 128 + j]);
  } else if (t >= 20480 && t < 36864) { // A3 main = Wn1[12:140]^T
    int t2 = t - 20480; int j = t2 >> 7, k = t2 & 127;
    wsA[t] = f2bf(Wn1[(12 + k) * 128 + j]);
  }
}

// ---------------- main fused kernel ----------------
#define NTILES 8192   // 262144 rows / 32 rows per tile
#define GRID   768    // 3 WGs/CU fully resident; ~10.7 tiles per WG

__global__ __launch_bounds__(256) __attribute__((amdgpu_waves_per_eu(3, 3)))
void gn_main(
    const float* __restrict__ x, const float* __restrict__ u,
    const float* __restrict__ nmean, const float* __restrict__ nstd,
    const float* __restrict__ emean, const float* __restrict__ estd,
    const float* __restrict__ be2, const float* __restrict__ bn2,
    const unsigned short* __restrict__ wsA,
    float* __restrict__ out)
{
  __shared__ __align__(16) unsigned short bufE1[32 * 128];  // 8KB
  __shared__ __align__(16) unsigned short bufE2[32 * 128];  // 8KB
  __shared__ __align__(16) unsigned short aLDS[2560];       // A1c|A3e|wn2cols, 5KB
  __shared__ __align__(16) float pd[256];                   // [Mq][row][c], 1KB

  const int tid  = threadIdx.x;
  const int lane = tid & 63;
  const int Mq   = tid >> 6;     // wave = feature quarter 0..3
  const int c15  = lane & 15;
  const int g    = lane >> 4;    // 0..3

  const int jbw = Mq * 32;

  // ---- copy compact A-images + wn2 cols into LDS (one time) ----
  for (int t = tid; t < 1280; t += 256)
    ((unsigned*)aLDS)[t] = ((const unsigned*)wsA)[t];

  // ---- resident A-operand fragments: A2, A3-main (64 AGPRs) ----
  bf16x8 A2f[2][4], A3f[2][4];
  #pragma unroll
  for (int m = 0; m < 2; ++m) {
    int j = jbw + m * 16 + c15;
    #pragma unroll
    for (int kk = 0; kk < 4; ++kk) {
      A2f[m][kk] = *(const bf16x8*)(wsA + 4096  + j * 128 + kk * 32 + g * 8);
      A3f[m][kk] = *(const bf16x8*)(wsA + 20480 + j * 128 + kk * 32 + g * 8);
    }
  }

  const float nm0 = nmean[0], nm1 = nmean[1];
  const float is0 = 1.0f / nstd[0], is1 = 1.0f / nstd[1];
  const float em0 = emean[0], ie0 = 1.0f / estd[0];
  const float cea1 = (0.0f - emean[1]) / estd[1];
  const float cea2 = (0.0f - emean[2]) / estd[2];
  const float bn20 = bn2[0], bn21 = bn2[1];
  const unsigned cpkw = cvtpk(cea2, 1.0f);   // B dword3: [cea2, 1.0]

  // ---- prefetch first tile's x/u ----
  float4 xv[2]; float uv[2];
  if (g == 0) {
    #pragma unroll
    for (int n = 0; n < 2; ++n) {
      int b = blockIdx.x * 16 + n * 8 + (c15 >> 1);
      xv[n] = *(const float4*)(x + b * 4);
      uv[n] = u[b];
    }
  }
  __syncthreads();   // aLDS ready

  for (int tile = blockIdx.x; tile < NTILES; tile += GRID) {
    const int rowbase = tile * 32;

    // opaque LDS offset: stop LICM from hoisting loop-invariant aLDS reads into regs
    unsigned aoff = 0;
    asm volatile("" : "+v"(aoff));
    const char* aB = (const char*)aLDS + aoff;

    // ---------- A1 transient fragments (LDS; g>0 garbage harmless: B zero there) ----------
    bf16x8 A1t[2];
    #pragma unroll
    for (int m = 0; m < 2; ++m) {
      U4B ta; ta.u = *(const uint4*)(aB + (jbw + m * 16 + c15) * 16);
      A1t[m] = ta.b;
    }

    // ---------- build G1 B-operands in registers ----------
    unsigned pks[2];
    bf16x8 Bv[2];
    #pragma unroll
    for (int n = 0; n < 2; ++n) {
      uint4 bu = (uint4){0u, 0u, 0u, 0u};
      if (g == 0) {                     // only k=0..7 nonzero; g==0 lanes hold them
        float a0 = (xv[n].x - nm0) * is0;   // node0 theta
        float a1 = (xv[n].z - nm1) * is1;   // node0 v
        float b0 = (xv[n].y - nm0) * is0;   // node1 theta
        float b1 = (xv[n].w - nm1) * is1;   // node1 v
        bool  e  = (c15 & 1);               // row parity = edge index
        float s0 = e ? b0 : a0, s1 = e ? b1 : a1;   // sender  feats
        float r0 = e ? a0 : b0, r1 = e ? a1 : b1;   // receiver feats
        float ea0 = (uv[n] - em0) * ie0;
        bu.x = cvtpk(s0, s1);
        bu.y = cvtpk(r0, r1);
        bu.z = cvtpk(ea0, cea1);
        bu.w = cpkw;
      }
      pks[n] = bu.x;                    // sender feats, reused as G3 node feats
      U4B t; t.u = bu; Bv[n] = t.b;
    }

    // ---------- prefetch next tile's x/u ----------
    {
      int nt = tile + GRID;
      if (nt < NTILES && g == 0) {
        #pragma unroll
        for (int n = 0; n < 2; ++n) {
          int b = nt * 16 + n * 8 + (c15 >> 1);
          xv[n] = *(const float4*)(x + b * 4);
          uv[n] = u[b];
        }
      }
    }

    f32x4 acc[2][2];

    // ---------- G1: e1 = relu(A1 @ in32) -> bufE1 ----------
    #pragma unroll
    for (int m = 0; m < 2; ++m)
      #pragma unroll
      for (int n = 0; n < 2; ++n) acc[m][n] = (f32x4){0.f, 0.f, 0.f, 0.f};
    #pragma unroll
    for (int n = 0; n < 2; ++n)
      #pragma unroll
      for (int m = 0; m < 2; ++m)
        acc[m][n] = __builtin_amdgcn_mfma_f32_16x16x32_bf16(A1t[m], Bv[n], acc[m][n], 0, 0, 0);
    #pragma unroll
    for (int m = 0; m < 2; ++m) {
      int jb2 = (jbw + m * 16 + g * 4) * 2;
      #pragma unroll
      for (int n = 0; n < 2; ++n) {
        int row = n * 16 + c15;
        f32x4 v = acc[m][n];
        uint2 pk;
        pk.x = cvtpk(fmaxf(v[0], 0.f), fmaxf(v[1], 0.f));
        pk.y = cvtpk(fmaxf(v[2], 0.f), fmaxf(v[3], 0.f));
        *(uint2*)((char*)bufE1 + row * 256 + (jb2 ^ ((row & 7) << 4))) = pk;
      }
    }
    __syncthreads();                                   // bar1: e1 ready

    // ---------- G2: e2 = relu(A2 @ e1 + be2) -> bufE2 (be2 as C-init) ----------
    #pragma unroll
    for (int m = 0; m < 2; ++m) {
      f32x4 bz = *(const f32x4*)(be2 + jbw + m * 16 + g * 4);
      acc[m][0] = bz; acc[m][1] = bz;
    }
    __builtin_amdgcn_s_setprio(1);
    #pragma unroll
    for (int n = 0; n < 2; ++n) {
      int row = n * 16 + c15;
      int rb = row * 256, sw = (row & 7) << 4;
      #pragma unroll
      for (int kk = 0; kk < 4; ++kk) {
        bf16x8 B = *(const bf16x8*)((const char*)bufE1 + rb + ((kk * 64 + g * 16) ^ sw));
        #pragma unroll
        for (int m = 0; m < 2; ++m)
          acc[m][n] = __builtin_amdgcn_mfma_f32_16x16x32_bf16(A2f[m][kk], B, acc[m][n], 0, 0, 0);
      }
    }
    __builtin_amdgcn_s_setprio(0);
    #pragma unroll
    for (int m = 0; m < 2; ++m) {
      int jb2 = (jbw + m * 16 + g * 4) * 2;
      #pragma unroll
      for (int n = 0; n < 2; ++n) {
        int row = n * 16 + c15;
        f32x4 v = acc[m][n];
        uint2 pk;
        pk.x = cvtpk(fmaxf(v[0], 0.f), fmaxf(v[1], 0.f));
        pk.y = cvtpk(fmaxf(v[2], 0.f), fmaxf(v[3], 0.f));
        *(uint2*)((char*)bufE2 + row * 256 + (jb2 ^ ((row & 7) << 4))) = pk;
      }
    }
    __syncthreads();                                   // bar2: e2 ready

    // ---------- G3: hdd = relu(A3 @ [e2[row^1]; sender,1]) ; fused G4 dot ----------
    bf16x8 A3et[2];
    #pragma unroll
    for (int m = 0; m < 2; ++m) {       // transient ext fragments (no mask: B4 zero for g>0)
      U4B ta; ta.u = *(const uint4*)(aB + 2048 + (jbw + m * 16 + c15) * 16);
      A3et[m] = ta.b;
    }
    #pragma unroll
    for (int m = 0; m < 2; ++m)
      #pragma unroll
      for (int n = 0; n < 2; ++n) acc[m][n] = (f32x4){0.f, 0.f, 0.f, 0.f};
    __builtin_amdgcn_s_setprio(1);
    #pragma unroll
    for (int n = 0; n < 2; ++n) {
      int rsw = (n * 16 + c15) ^ 1;     // aggregation = paired-row swap
      int rb = rsw * 256, sw = (rsw & 7) << 4;
      #pragma unroll
      for (int kk = 0; kk < 4; ++kk) {
        bf16x8 B = *(const bf16x8*)((const char*)bufE2 + rb + ((kk * 64 + g * 16) ^ sw));
        #pragma unroll
        for (int m = 0; m < 2; ++m)
          acc[m][n] = __builtin_amdgcn_mfma_f32_16x16x32_bf16(A3f[m][kk], B, acc[m][n], 0, 0, 0);
      }
      // K-chunk 4: node feats (= sender feats saved from B-build) + const-1 (bn1 col)
      uint4 b4u = (uint4){0u, 0u, 0u, 0u};
      if (g == 0) { b4u.x = pks[n]; b4u.y = 0x00003F80u; }
      U4B t4; t4.u = b4u;
      #pragma unroll
      for (int m = 0; m < 2; ++m)
        acc[m][n] = __builtin_amdgcn_mfma_f32_16x16x32_bf16(A3et[m], t4.b, acc[m][n], 0, 0, 0);
    }
    __builtin_amdgcn_s_setprio(0);

    // fused G4: p[n][c] = sum_j relu(hdd[j]) * Wn2[j][c] over this wave's 8 j per lane
    {
      float p0[2] = {0.f, 0.f}, p1[2] = {0.f, 0.f};
      #pragma unroll
      for (int m = 0; m < 2; ++m) {
        int jo = (jbw + m * 16 + g * 4) * 4;           // byte offset into f32[128]
        f32x4 w0 = *(const f32x4*)(aB + 4096 + jo);    // Wn2 col0
        f32x4 w1 = *(const f32x4*)(aB + 4608 + jo);    // Wn2 col1
        #pragma unroll
        for (int n = 0; n < 2; ++n) {
          f32x4 v = acc[m][n];
          #pragma unroll
          for (int r = 0; r < 4; ++r) {
            float h = fmaxf(v[r], 0.f);
            p0[n] += h * w0[r];
            p1[n] += h * w1[r];
          }
        }
      }
      #pragma unroll
      for (int n = 0; n < 2; ++n) {                    // reduce over g (4 lane-groups)
        p0[n] += __shfl_xor(p0[n], 16, 64); p0[n] += __shfl_xor(p0[n], 32, 64);
        p1[n] += __shfl_xor(p1[n], 16, 64); p1[n] += __shfl_xor(p1[n], 32, 64);
      }
      if (g == 0) {
        #pragma unroll
        for (int n = 0; n < 2; ++n) {
          float2 w; w.x = p0[n]; w.y = p1[n];
          *(float2*)(pd + Mq * 64 + (n * 16 + c15) * 2) = w;
        }
      }
    }
    __syncthreads();                                   // bar3: pd ready

    // ---------- final: combine quarters, add bn2 and x, store (wave 0) ----------
    if (tid < 64) {
      int row = tid >> 1, c = tid & 1;
      float d = pd[row * 2 + c] + pd[64 + row * 2 + c]
              + pd[128 + row * 2 + c] + pd[192 + row * 2 + c] + (c ? bn21 : bn20);
      int gr = rowbase + row;
      int bidx = gr >> 1, k = gr & 1;
      int gi = bidx * 4 + k + 2 * c;
      out[gi] = x[gi] + d;
    }
    // next G1 writes bufE1 (last read before bar2); pd rewritten only after next bar2. Safe.
  }
}

extern "C" void kernel_launch(void* const* d_in, const int* in_sizes, int n_in,
                              void* d_out, int out_size, void* d_ws, size_t ws_size,
                              hipStream_t stream) {
  const float* x   = (const float*)d_in[0];
  const float* u   = (const float*)d_in[1];
  const float* nm  = (const float*)d_in[2];
  const float* ns  = (const float*)d_in[3];
  const float* em  = (const float*)d_in[4];
  const float* es  = (const float*)d_in[5];
  const float* We1 = (const float*)d_in[6];
  const float* be1 = (const float*)d_in[7];
  const float* We2 = (const float*)d_in[8];
  const float* be2 = (const float*)d_in[9];
  const float* Wn1 = (const float*)d_in[10];
  const float* bn1 = (const float*)d_in[11];
  const float* Wn2 = (const float*)d_in[12];
  const float* bn2 = (const float*)d_in[13];
  unsigned short* wsA = (unsigned short*)d_ws;   // needs 73728 bytes
  float* out = (float*)d_out;

  gn_prep<<<144, 256, 0, stream>>>(We1, be1, We2, Wn1, bn1, Wn2, wsA);
  gn_main<<<GRID, 256, 0, stream>>>(x, u, nm, ns, em, es, be2, bn2, wsA, out);
}